// Round 11
// baseline (251.899 us; speedup 1.0000x reference)
//
#include <hip/hip_runtime.h>

#define BATCH 8
#define SDIM 2048
#define KDIM 2048
#define NDIM 2048

typedef __bf16 bf16_t;
typedef bf16_t bf16x4 __attribute__((ext_vector_type(4)));
typedef bf16_t bf16x8 __attribute__((ext_vector_type(8)));
typedef float f32x4 __attribute__((ext_vector_type(4)));
typedef float f32x8 __attribute__((ext_vector_type(8)));
typedef unsigned short u16x8 __attribute__((ext_vector_type(8)));

__device__ __forceinline__ void gl_lds16(const void* g, void* l) {
    // async global->LDS DMA, 16B/lane; LDS dest = wave-uniform base + lane*16
    __builtin_amdgcn_global_load_lds(
        (__attribute__((address_space(1))) void*)g,
        (__attribute__((address_space(3))) void*)l,
        16, 0, 0);
}

// ---------------- Pass 1a: A fp32 -> bf16 (elementwise) ----------------
__global__ __launch_bounds__(256)
void cvtA_kernel(const float* __restrict__ A, bf16_t* __restrict__ Abf) {
    const size_t total8 = (size_t)BATCH * SDIM * KDIM / 8;
    const size_t stride = (size_t)gridDim.x * 256;
    for (size_t i = (size_t)blockIdx.x * 256 + threadIdx.x; i < total8; i += stride) {
        f32x8 v = *reinterpret_cast<const f32x8*>(A + i * 8);
        *reinterpret_cast<bf16x8*>(Abf + i * 8) = __builtin_convertvector(v, bf16x8);
    }
}

// ------------- Pass 1b: B fp32 [K][N] -> bf16 B^T [N][K] ----------------
__global__ __launch_bounds__(256)
void cvtBT_kernel(const float* __restrict__ B, bf16_t* __restrict__ Bt) {
    __shared__ alignas(16) bf16_t T[64][72];
    const int gid = blockIdx.x;
    const int batch = gid & 7;
    const int tile = gid >> 3;
    const int k0g = (tile >> 5) * 64;
    const int n0g = (tile & 31) * 64;
    const float* Bb = B + (size_t)batch * KDIM * NDIM + (size_t)k0g * NDIM + n0g;
    bf16_t* Tb = Bt + (size_t)batch * NDIM * KDIM + (size_t)n0g * KDIM + k0g;

    const int t = threadIdx.x;
    const int kq = t & 15;
    const int nq = t >> 4;
    f32x4 v[4];
#pragma unroll
    for (int r = 0; r < 4; ++r)
        v[r] = *reinterpret_cast<const f32x4*>(Bb + (size_t)(kq * 4 + r) * NDIM + nq * 4);
#pragma unroll
    for (int j = 0; j < 4; ++j) {
        bf16x4 w = {(bf16_t)v[0][j], (bf16_t)v[1][j], (bf16_t)v[2][j], (bf16_t)v[3][j]};
        *reinterpret_cast<bf16x4*>(&T[nq * 4 + j][kq * 4]) = w;
    }
    __syncthreads();
    const int n = t >> 2, kc = t & 3;
    bf16x8 o0 = *reinterpret_cast<const bf16x8*>(&T[n][kc * 16]);
    bf16x8 o1 = *reinterpret_cast<const bf16x8*>(&T[n][kc * 16 + 8]);
    *reinterpret_cast<bf16x8*>(Tb + (size_t)n * KDIM + kc * 16) = o0;
    *reinterpret_cast<bf16x8*>(Tb + (size_t)n * KDIM + kc * 16 + 8) = o1;
}

// -------- Pass 2: m201-template port. 256x256, BK=64, 2 LDS buffers -----
// 8 waves (2M x 4N). Per K-tile (64 k): 4 quadrant phases, 16 MFMA each.
// Quadrant rotation Q0=(A0,B0) Q1=(A0,B1) Q2=(A1,B1) Q3=(A1,B0):
//   ph0: read A0[8]+B0[4]; stage pair1(j+1); BAR; lgkm0; MFMA Q0; BAR
//   ph1: read B1[4];       stage pair2(j+1); BAR; lgkm0; MFMA Q1; BAR
//   ph2: read A1[8];       stage pair3(j+1); BAR; lgkm0; MFMA Q2; BAR
//   ph3: (no reads)        stage pair0(j+2); vmcnt(2); BAR; MFMA Q3; BAR
// sched_barrier(0) pins reads/stages above BAR and MFMA below lgkm0 (rule
// 18: raw s_barrier is not an LLVM scheduling fence). vmcnt(2) once per
// K-tile: leaves pair0(j+2) in flight, proves all 8 loads of j+1 landed
// (they are the older outstanding ops). WAR: ph3 has no reads, so the
// early pair0 stage targets a region whose readers all passed ph2's
// closing barrier; pairs1-3 overwrite buf P^1 consumed by tile j-1,
// whose last reads completed before ph2(j-1)'s closing barrier.
// LDS layout per buffer: A then B, each [rowOct][kOct][16 rows][16B]
// chunks - DMA-linear (chunk index == inst*512 + tid), fragment reads
// 256B-contiguous per 16-lane group -> zero bank conflict.
#define VM2 asm volatile("s_waitcnt vmcnt(2)" ::: "memory")
#define VM0 asm volatile("s_waitcnt vmcnt(0)" ::: "memory")
#define BAR __builtin_amdgcn_s_barrier()
#define SB0 __builtin_amdgcn_sched_barrier(0)
#define LG0 do { asm volatile("s_waitcnt lgkmcnt(0)" ::: "memory"); SB0; } while (0)
#define NOOP ((void)0)

__global__ __launch_bounds__(512, 2)
void bgemm_t201(const bf16_t* __restrict__ A, const bf16_t* __restrict__ Bt,
                float* __restrict__ O) {
    __shared__ alignas(16) bf16_t lds[65536];   // 2 x 64KB = 128 KiB

    const int tid = threadIdx.x;
    const int gid = blockIdx.x;
    const int batch = gid & 7;          // one batch per XCD
    const int t = gid >> 3;
    const int bm = (t >> 3) * 256;
    const int bn = (t & 7) * 256;

    const int lane = tid & 63;
    const int wid = tid >> 6;           // 0..7
    const int wr = wid >> 2;            // 0..1 (128-row half)
    const int wc = wid & 3;             // 0..3 (64-col quarter)
    const int lr = lane & 15;
    const int lq = lane >> 4;

    const bf16_t* Ab = A + (size_t)batch * SDIM * KDIM;
    const bf16_t* Bb = Bt + (size_t)batch * NDIM * KDIM;
    float* Ob = O + (size_t)batch * SDIM * NDIM;

    // staging source per thread: inst i covers tile rows 64i..64i+63
    const bf16_t* aStg = Ab + (size_t)(bm + ((tid >> 7) << 4) + (tid & 15)) * KDIM
                            + ((tid >> 4) & 7) * 8;
    const bf16_t* bStg = Bb + (size_t)(bn + ((tid >> 7) << 4) + (tid & 15)) * KDIM
                            + ((tid >> 4) & 7) * 8;

// stage inst: A inst I into buf PD at K-tile KT (B same + 16384 elems)
#define STG_A(PD_, I_, KT_) gl_lds16(aStg + (size_t)(I_) * 64 * KDIM + (size_t)(KT_) * 64, \
                                     &lds[(PD_) * 32768 + (I_) * 4096 + wid * 512])
#define STG_B(PD_, I_, KT_) gl_lds16(bStg + (size_t)(I_) * 64 * KDIM + (size_t)(KT_) * 64, \
                                     &lds[(PD_) * 32768 + 16384 + (I_) * 4096 + wid * 512])

    f32x4 acc[8][4];
#pragma unroll
    for (int m = 0; m < 8; ++m)
#pragma unroll
        for (int n = 0; n < 4; ++n)
            acc[m][n] = (f32x4){0.f, 0.f, 0.f, 0.f};

    // fragment registers: A half (4m x 2ks), B halves (2n x 2ks each)
    bf16x8 afr[4][2], b0f[2][2], b1f[2][2];

#define RD_A(P_, MH_) do { \
    _Pragma("unroll") \
    for (int mq_ = 0; mq_ < 4; ++mq_) \
        _Pragma("unroll") \
        for (int ks_ = 0; ks_ < 2; ++ks_) \
            afr[mq_][ks_] = *reinterpret_cast<const bf16x8*>( \
                &lds[(P_) * 32768 + ((wr * 8 + (MH_) * 4 + mq_) * 128 \
                                     + (ks_ * 4 + lq) * 16 + lr) * 8]); \
} while (0)

#define RD_B(P_, NH_, BF_) do { \
    _Pragma("unroll") \
    for (int nq_ = 0; nq_ < 2; ++nq_) \
        _Pragma("unroll") \
        for (int ks_ = 0; ks_ < 2; ++ks_) \
            BF_[nq_][ks_] = *reinterpret_cast<const bf16x8*>( \
                &lds[(P_) * 32768 + 16384 + ((wc * 4 + (NH_) * 2 + nq_) * 128 \
                                             + (ks_ * 4 + lq) * 16 + lr) * 8]); \
} while (0)

#define MFMA_Q(MB_, NB_, BF_) do { \
    __builtin_amdgcn_s_setprio(1); \
    _Pragma("unroll") \
    for (int mq_ = 0; mq_ < 4; ++mq_) \
        _Pragma("unroll") \
        for (int nq_ = 0; nq_ < 2; ++nq_) \
            _Pragma("unroll") \
            for (int ks_ = 0; ks_ < 2; ++ks_) \
                acc[(MB_) + mq_][(NB_) + nq_] = __builtin_amdgcn_mfma_f32_16x16x32_bf16( \
                    afr[mq_][ks_], BF_[nq_][ks_], acc[(MB_) + mq_][(NB_) + nq_], 0, 0, 0); \
    __builtin_amdgcn_s_setprio(0); \
} while (0)

// BODY computes tile in buf P_; S1_-S3_ stage pairs1-3 of next tile,
// S0N_ stages pair0 of tile-after-next, VM_ is the once-per-tile vmcnt.
#define BODY(P_, S1_, S2_, S3_, S0N_, VM_) do { \
    /* ph0 */ SB0; RD_A(P_, 0); RD_B(P_, 0, b0f); S1_; SB0; BAR; LG0; \
              MFMA_Q(0, 0, b0f); SB0; BAR; \
    /* ph1 */ SB0; RD_B(P_, 1, b1f); S2_; SB0; BAR; LG0; \
              MFMA_Q(0, 2, b1f); SB0; BAR; \
    /* ph2 */ SB0; RD_A(P_, 1); S3_; SB0; BAR; LG0; \
              MFMA_Q(4, 2, b1f); SB0; BAR; \
    /* ph3 */ SB0; S0N_; VM_; SB0; BAR; SB0; \
              MFMA_Q(4, 0, b0f); SB0; BAR; \
} while (0)

    // prologue: all 8 loads of tile0 -> buf0; pair0 of tile1 -> buf1
    STG_A(0, 0, 0); STG_A(0, 1, 0); STG_A(0, 2, 0); STG_A(0, 3, 0);
    STG_B(0, 0, 0); STG_B(0, 1, 0); STG_B(0, 2, 0); STG_B(0, 3, 0);
    STG_A(1, 0, 1); STG_A(1, 1, 1);
    VM2;                                 // tile0 landed; pair0(t1) in flight
    BAR;

#pragma unroll 1
    for (int j = 0; j < 30; j += 2) {    // tiles j (buf0) and j+1 (buf1)
        BODY(0,
             (STG_A(1, 2, j + 1), STG_A(1, 3, j + 1)),
             (STG_B(1, 0, j + 1), STG_B(1, 1, j + 1)),
             (STG_B(1, 2, j + 1), STG_B(1, 3, j + 1)),
             (STG_A(0, 0, j + 2), STG_A(0, 1, j + 2)), VM2);
        BODY(1,
             (STG_A(0, 2, j + 2), STG_A(0, 3, j + 2)),
             (STG_B(0, 0, j + 2), STG_B(0, 1, j + 2)),
             (STG_B(0, 2, j + 2), STG_B(0, 3, j + 2)),
             (STG_A(1, 0, j + 3), STG_A(1, 1, j + 3)), VM2);
    }
    // tile 30: stage pairs1-3 of t31; no further pair0; drain fully
    BODY(0,
         (STG_A(1, 2, 31), STG_A(1, 3, 31)),
         (STG_B(1, 0, 31), STG_B(1, 1, 31)),
         (STG_B(1, 2, 31), STG_B(1, 3, 31)),
         NOOP, VM0);
    // tile 31: pure compute
    BODY(1, NOOP, NOOP, NOOP, NOOP, NOOP);

    // epilogue: C/D layout col=lane&15, row=(lane>>4)*4+reg (R1-verified)
#pragma unroll
    for (int m = 0; m < 8; ++m) {
        const int row0 = bm + wr * 128 + m * 16 + lq * 4;
#pragma unroll
        for (int n = 0; n < 4; ++n) {
            const int col = bn + wc * 64 + n * 16 + lr;
#pragma unroll
            for (int j = 0; j < 4; ++j)
                Ob[(size_t)(row0 + j) * NDIM + col] = acc[m][n][j];
        }
    }
#undef BODY
#undef MFMA_Q
#undef RD_B
#undef RD_A
#undef STG_B
#undef STG_A
}

// ---------------- Fallback: R1 fused kernel (proven) --------------------
__device__ __forceinline__ unsigned short f2bf(float f) {
    unsigned int u = __builtin_bit_cast(unsigned int, f);
    u += 0x7fffu + ((u >> 16) & 1u);
    return (unsigned short)(u >> 16);
}

__global__ __launch_bounds__(256, 2)
void bgemm_fused(const float* __restrict__ A, const float* __restrict__ B,
                 float* __restrict__ O) {
    __shared__ alignas(16) unsigned short Asl[2][4 * 128 * 8];
    __shared__ alignas(16) unsigned short Bsl[2][4 * 128 * 8];
    const int tid = threadIdx.x;
    const int gid = blockIdx.x;
    const int batch = gid & 7;
    const int t = gid >> 3;
    const int bm = (t >> 4) * 128;
    const int bn = (t & 15) * 128;
    const float* Ab = A + (size_t)batch * SDIM * KDIM;
    const float* Bb = B + (size_t)batch * KDIM * NDIM;
    float* Ob = O + (size_t)batch * SDIM * NDIM;
    const int lane = tid & 63;
    const int wid = tid >> 6;
    const int wr = wid >> 1, wc = wid & 1;
    const int lr = lane & 15, lq = lane >> 4;
    const int r0 = tid & 127, h0 = tid >> 7;
    u16x8 areg[2], breg[2];
    f32x4 acc[4][4];
#pragma unroll
    for (int m = 0; m < 4; ++m)
#pragma unroll
        for (int n = 0; n < 4; ++n) acc[m][n] = (f32x4){0.f, 0.f, 0.f, 0.f};
    auto stage_regs = [&](int kt) {
        const int k0 = kt * 32;
        const float* ap = Ab + (size_t)(bm + r0) * KDIM + k0 + h0 * 16;
        float4 a0 = *reinterpret_cast<const float4*>(ap + 0);
        float4 a1 = *reinterpret_cast<const float4*>(ap + 4);
        float4 a2 = *reinterpret_cast<const float4*>(ap + 8);
        float4 a3 = *reinterpret_cast<const float4*>(ap + 12);
        u16x8 u;
        u[0]=f2bf(a0.x);u[1]=f2bf(a0.y);u[2]=f2bf(a0.z);u[3]=f2bf(a0.w);
        u[4]=f2bf(a1.x);u[5]=f2bf(a1.y);u[6]=f2bf(a1.z);u[7]=f2bf(a1.w);
        areg[0]=u;
        u[0]=f2bf(a2.x);u[1]=f2bf(a2.y);u[2]=f2bf(a2.z);u[3]=f2bf(a2.w);
        u[4]=f2bf(a3.x);u[5]=f2bf(a3.y);u[6]=f2bf(a3.z);u[7]=f2bf(a3.w);
        areg[1]=u;
        const float* bp = Bb + (size_t)(k0 + h0 * 16) * NDIM + bn + r0;
        float f[16];
#pragma unroll
        for (int j = 0; j < 16; ++j) f[j] = bp[(size_t)j * NDIM];
        u16x8 v;
#pragma unroll
        for (int j = 0; j < 8; ++j) v[j] = f2bf(f[j]);
        breg[0] = v;
#pragma unroll
        for (int j = 0; j < 8; ++j) v[j] = f2bf(f[8 + j]);
        breg[1] = v;
    };
    auto regs_to_lds = [&](int b) {
#pragma unroll
        for (int o = 0; o < 2; ++o) {
            *reinterpret_cast<u16x8*>(&Asl[b][((h0*2+o)*128 + r0)*8]) = areg[o];
            *reinterpret_cast<u16x8*>(&Bsl[b][((h0*2+o)*128 + r0)*8]) = breg[o];
        }
    };
    stage_regs(0);
    regs_to_lds(0);
    int buf = 0;
    for (int kt = 0; kt < KDIM / 32; ++kt) {
        if (kt + 1 < KDIM / 32) stage_regs(kt + 1);
        __syncthreads();
        bf16x8 af[4], bfv[4];
#pragma unroll
        for (int m = 0; m < 4; ++m)
            af[m] = *reinterpret_cast<const bf16x8*>(&Asl[buf][(lq*128 + wr*64 + m*16 + lr)*8]);
#pragma unroll
        for (int n = 0; n < 4; ++n)
            bfv[n] = *reinterpret_cast<const bf16x8*>(&Bsl[buf][(lq*128 + wc*64 + n*16 + lr)*8]);
#pragma unroll
        for (int m = 0; m < 4; ++m)
#pragma unroll
            for (int n = 0; n < 4; ++n)
                acc[m][n] = __builtin_amdgcn_mfma_f32_16x16x32_bf16(af[m], bfv[n], acc[m][n], 0, 0, 0);
        if (kt + 1 < KDIM / 32) regs_to_lds(buf ^ 1);
        buf ^= 1;
    }
#pragma unroll
    for (int m = 0; m < 4; ++m) {
        const int row0 = bm + wr * 64 + m * 16 + lq * 4;
#pragma unroll
        for (int n = 0; n < 4; ++n) {
            const int col = bn + wc * 64 + n * 16 + lr;
#pragma unroll
            for (int j = 0; j < 4; ++j)
                Ob[(size_t)(row0 + j) * NDIM + col] = acc[m][n][j];
        }
    }
}

extern "C" void kernel_launch(void* const* d_in, const int* in_sizes, int n_in,
                              void* d_out, int out_size, void* d_ws, size_t ws_size,
                              hipStream_t stream) {
    const float* a = (const float*)d_in[0];
    const float* b = (const float*)d_in[1];
    float* o = (float*)d_out;
    const size_t half = (size_t)BATCH * SDIM * KDIM * sizeof(bf16_t);  // 64 MiB
    if (ws_size >= 2 * half) {
        bf16_t* Abf = (bf16_t*)d_ws;
        bf16_t* Bt = (bf16_t*)((char*)d_ws + half);
        hipLaunchKernelGGL(cvtA_kernel, dim3(4096), dim3(256), 0, stream, a, Abf);
        hipLaunchKernelGGL(cvtBT_kernel, dim3(8192), dim3(256), 0, stream, b, Bt);
        hipLaunchKernelGGL(bgemm_t201, dim3(512), dim3(512), 0, stream, Abf, Bt, o);
    } else {
        hipLaunchKernelGGL(bgemm_fused, dim3(2048), dim3(256), 0, stream, a, b, o);
    }
}